// Round 7
// baseline (1094.819 us; speedup 1.0000x reference)
//
#include <hip/hip_runtime.h>
#include <hip/hip_bf16.h>
#include <math.h>

#define BN_EPS 1e-5f
#define RES_SCALE 0.7f

typedef float f4 __attribute__((ext_vector_type(4)));
typedef short s8 __attribute__((ext_vector_type(8)));

__device__ inline short f2bf(float f) {
    __hip_bfloat16 h = __float2bfloat16(f);
    return *reinterpret_cast<short*>(&h);
}

// ---------------- init ----------------
__global__ __launch_bounds__(256) void k_zero(int* counts, int* cursor, float* stats, int N, int S) {
    int i = blockIdx.x * 256 + threadIdx.x;
    if (i < N) { counts[i] = 0; cursor[i] = 0; }
    if (i < S) stats[i] = 0.0f;
}

// ---------------- degree / CSR build ----------------
__global__ __launch_bounds__(256) void k_count(const int* __restrict__ edges, int E, int* __restrict__ counts) {
    int e = blockIdx.x * 256 + threadIdx.x;
    if (e < E) atomicAdd(&counts[edges[E + e]], 1);   // dst = edges[1][e]
}

// exclusive scan of counts -> rowstart (chunk = 1024 per block); also emits dinv
__global__ __launch_bounds__(256) void k_scan1(const int* __restrict__ counts, int* __restrict__ bsum,
                                               float* __restrict__ dinv, int N) {
    __shared__ int sd[256];
    int t = threadIdx.x;
    int base = blockIdx.x * 1024 + t * 4;
    int s = 0;
    if (base + 3 < N) {
        int4 v = *(const int4*)(counts + base);
        s = v.x + v.y + v.z + v.w;
        f4 d;
        d.x = rsqrtf((float)v.x + 1.0f);
        d.y = rsqrtf((float)v.y + 1.0f);
        d.z = rsqrtf((float)v.z + 1.0f);
        d.w = rsqrtf((float)v.w + 1.0f);
        *(f4*)(dinv + base) = d;
    } else {
        for (int j = 0; j < 4; ++j) if (base + j < N) {
            int cv = counts[base + j];
            s += cv;
            dinv[base + j] = rsqrtf((float)cv + 1.0f);
        }
    }
    sd[t] = s; __syncthreads();
    for (int off = 128; off > 0; off >>= 1) { if (t < off) sd[t] += sd[t + off]; __syncthreads(); }
    if (t == 0) bsum[blockIdx.x] = sd[0];
}

__global__ void k_scan2(int* bsum, int B, int* rowstart, int N) {
    if (threadIdx.x == 0 && blockIdx.x == 0) {
        int run = 0;
        for (int b = 0; b < B; ++b) { int v = bsum[b]; bsum[b] = run; run += v; }
        rowstart[N] = run;
    }
}

__global__ __launch_bounds__(256) void k_scan3(const int* __restrict__ counts, const int* __restrict__ bsum,
                                               int* __restrict__ rowstart, int N) {
    __shared__ int sd[256];
    int t = threadIdx.x;
    int base = blockIdx.x * 1024 + t * 4;
    int v0 = 0, v1 = 0, v2 = 0, v3 = 0;
    if (base + 3 < N) { int4 v = *(const int4*)(counts + base); v0 = v.x; v1 = v.y; v2 = v.z; v3 = v.w; }
    else {
        if (base < N) v0 = counts[base];
        if (base + 1 < N) v1 = counts[base + 1];
        if (base + 2 < N) v2 = counts[base + 2];
        if (base + 3 < N) v3 = counts[base + 3];
    }
    int s = v0 + v1 + v2 + v3;
    sd[t] = s; __syncthreads();
    for (int off = 1; off < 256; off <<= 1) {
        int add = (t >= off) ? sd[t - off] : 0;
        __syncthreads();
        sd[t] += add;
        __syncthreads();
    }
    int excl = sd[t] - s + bsum[blockIdx.x];
    if (base < N)     rowstart[base]     = excl;
    if (base + 1 < N) rowstart[base + 1] = excl + v0;
    if (base + 2 < N) rowstart[base + 2] = excl + v0 + v1;
    if (base + 3 < N) rowstart[base + 3] = excl + v0 + v1 + v2;
}

// scatter: CSR column list only (edge weight is folded into pre-scaled xw)
__global__ __launch_bounds__(256) void k_scatter(const int* __restrict__ edges, int E,
                                                 const int* __restrict__ rowstart, int* __restrict__ cursor,
                                                 int* __restrict__ colA) {
    int e = blockIdx.x * 256 + threadIdx.x;
    if (e >= E) return;
    int s = edges[e], d = edges[E + e];
    int pos = rowstart[d] + atomicAdd(&cursor[d], 1);
    colA[pos] = s;
}

// ---------------- W pre-transpose + bf16 convert: WT[n][k] = bf16(W[k][n]) ----------------
__global__ __launch_bounds__(256) void k_wt(const float* __restrict__ W0, const float* __restrict__ Wh,
                                            short* __restrict__ WT0, short* __restrict__ WTh, int K0) {
    __shared__ short Ts[64][72];
    int b = blockIdx.x, t = threadIdx.x;
    int nk0 = (K0 + 63) >> 6;
    const float* W; short* dst; int K, kt;
    if (b < nk0) { W = W0; dst = WT0; K = K0; kt = b * 64; }
    else { int l = b - nk0; W = Wh + (size_t)l * 64 * 64; dst = WTh + (size_t)l * 64 * 64; K = 64; kt = 0; }
    #pragma unroll
    for (int i = 0; i < 16; ++i) {
        int idx = t + i * 256;
        int r = idx >> 6, c = idx & 63;
        int gk = kt + r;
        Ts[c][r] = (gk < K) ? f2bf(W[(size_t)gk * 64 + c]) : (short)0;
    }
    __syncthreads();
    #pragma unroll
    for (int i = 0; i < 16; ++i) {
        int idx = t + i * 256;
        int n = idx >> 6, r = idx & 63;
        int gk = kt + r;
        if (gk < K) dst[(size_t)n * K + gk] = Ts[n][r];
    }
}

// ---------------- MFMA matmul: Cb[N,64] (bf16) = (X[N,K] @ WT^T) * dinv[row] ----------------
// K-tile 64; next-tile loads issued AFTER the first barrier so they stay in flight across
// the MFMA phase (compiler drains vmcnt at each barrier — issuing before a barrier kills
// the overlap; measured regression in R4).
__global__ __launch_bounds__(256) void k_mm(const float* __restrict__ X, const short* __restrict__ WT,
                                            const float* __restrict__ dinv,
                                            __hip_bfloat16* __restrict__ Cb, int N, int K) {
    __shared__ float Xs[64][68];   // row stride 272B (16B-aligned)
    __shared__ short Ws[64][72];   // row stride 144B (16B-aligned)
    int t = threadIdx.x;
    int w = t >> 6, lane = t & 63;
    int m = lane & 15, kq = lane >> 4;
    int row0 = blockIdx.x * 64;

    int xr = t >> 3, xc = t & 7;   // X staging: rows xr, xr+32; k-chunks xc*4, 32+xc*4 (float4)
    int wn = t >> 2, wc = t & 3;   // W staging: row wn, k-chunks wc*8, 32+wc*8 (8 bf16 = int4)

    f4 acc[4] = {};
    f4 px0, px1, px2, px3; int4 pw0, pw1;

    // prefetch k-tile 0
    {
        int gr0 = row0 + xr, gr1 = row0 + xr + 32;
        int gk0 = xc * 4, gk1 = 32 + xc * 4;
        px0 = (gr0 < N && gk0 < K) ? *(const f4*)(X + (size_t)gr0 * K + gk0) : (f4){};
        px1 = (gr0 < N && gk1 < K) ? *(const f4*)(X + (size_t)gr0 * K + gk1) : (f4){};
        px2 = (gr1 < N && gk0 < K) ? *(const f4*)(X + (size_t)gr1 * K + gk0) : (f4){};
        px3 = (gr1 < N && gk1 < K) ? *(const f4*)(X + (size_t)gr1 * K + gk1) : (f4){};
        int gw0 = wc * 8, gw1 = 32 + wc * 8;
        pw0 = (gw0 < K) ? *(const int4*)(WT + (size_t)wn * K + gw0) : make_int4(0, 0, 0, 0);
        pw1 = (gw1 < K) ? *(const int4*)(WT + (size_t)wn * K + gw1) : make_int4(0, 0, 0, 0);
    }

    for (int kt = 0; kt < K; kt += 64) {
        *(f4*)&Xs[xr][xc * 4]           = px0;
        *(f4*)&Xs[xr][32 + xc * 4]      = px1;
        *(f4*)&Xs[xr + 32][xc * 4]      = px2;
        *(f4*)&Xs[xr + 32][32 + xc * 4] = px3;
        *(int4*)&Ws[wn][wc * 8]         = pw0;
        *(int4*)&Ws[wn][32 + wc * 8]    = pw1;
        __syncthreads();

        int kn = kt + 64;
        if (kn < K) {
            int gr0 = row0 + xr, gr1 = row0 + xr + 32;
            int gk0 = kn + xc * 4, gk1 = kn + 32 + xc * 4;
            px0 = (gr0 < N && gk0 < K) ? *(const f4*)(X + (size_t)gr0 * K + gk0) : (f4){};
            px1 = (gr0 < N && gk1 < K) ? *(const f4*)(X + (size_t)gr0 * K + gk1) : (f4){};
            px2 = (gr1 < N && gk0 < K) ? *(const f4*)(X + (size_t)gr1 * K + gk0) : (f4){};
            px3 = (gr1 < N && gk1 < K) ? *(const f4*)(X + (size_t)gr1 * K + gk1) : (f4){};
            int gw0 = kn + wc * 8, gw1 = kn + 32 + wc * 8;
            pw0 = (gw0 < K) ? *(const int4*)(WT + (size_t)wn * K + gw0) : make_int4(0, 0, 0, 0);
            pw1 = (gw1 < K) ? *(const int4*)(WT + (size_t)wn * K + gw1) : make_int4(0, 0, 0, 0);
        }

        int arow = w * 16 + m;
        f4 a00 = *(const f4*)&Xs[arow][kq * 8];
        f4 a01 = *(const f4*)&Xs[arow][kq * 8 + 4];
        f4 a10 = *(const f4*)&Xs[arow][32 + kq * 8];
        f4 a11 = *(const f4*)&Xs[arow][32 + kq * 8 + 4];
        s8 av0, av1;
        #pragma unroll
        for (int j = 0; j < 4; ++j) {
            av0[j] = f2bf(a00[j]); av0[j + 4] = f2bf(a01[j]);
            av1[j] = f2bf(a10[j]); av1[j + 4] = f2bf(a11[j]);
        }
        #pragma unroll
        for (int ct = 0; ct < 4; ++ct) {
            s8 bv0 = *(const s8*)&Ws[ct * 16 + m][kq * 8];
            s8 bv1 = *(const s8*)&Ws[ct * 16 + m][32 + kq * 8];
            acc[ct] = __builtin_amdgcn_mfma_f32_16x16x32_bf16(av0, bv0, acc[ct], 0, 0, 0);
            acc[ct] = __builtin_amdgcn_mfma_f32_16x16x32_bf16(av1, bv1, acc[ct], 0, 0, 0);
        }
        __syncthreads();
    }

    // C/D layout: col = lane&15, row = (lane>>4)*4 + reg  [measured m89/m91]
    #pragma unroll
    for (int reg = 0; reg < 4; ++reg) {
        int gr = row0 + w * 16 + kq * 4 + reg;
        if (gr < N) {
            float di = dinv[gr];
            #pragma unroll
            for (int ct = 0; ct < 4; ++ct)
                Cb[(size_t)gr * 64 + ct * 16 + m] = __float2bfloat16(acc[ct][reg] * di);
        }
    }
}

// ---------------- CSR aggregation + fused BN stats ----------------
// One wave per dst row, grid-stride over rows (2048 blocks = 8 blocks/CU, ~6 rows/wave).
// 2 edges per wave-load (lanes 0-31 edge 2j, lanes 32-63 edge 2j+1). Per-row final agg
// values accumulate into per-column sum/sumsq registers; block-reduce in LDS; 128
// atomicAdds/block — removes the standalone k_stats pass (4 launches + 51 MB agg re-read).
__device__ inline const unsigned* g_rowsel(const unsigned* xw32, int c, int p, bool lo32) {
    unsigned o0 = (unsigned)__builtin_amdgcn_readlane(c, 2 * p) << 5;
    unsigned o1 = (unsigned)__builtin_amdgcn_readlane(c, 2 * p + 1) << 5;
    return xw32 + (lo32 ? o0 : o1);
}

__global__ __launch_bounds__(256) void k_gather(const __hip_bfloat16* __restrict__ xw, const int* __restrict__ colA,
                                                const int* __restrict__ rowstart,
                                                const float* __restrict__ dinv, float* __restrict__ agg,
                                                float* __restrict__ stats, int N, int NW) {
    int wid = (blockIdx.x * 256 + threadIdx.x) >> 6;
    int w = threadIdx.x >> 6;
    int lane = threadIdx.x & 63;
    const unsigned* xw32 = (const unsigned*)xw;
    int l31 = lane & 31;
    bool lo32 = lane < 32;

    float s0 = 0.f, s1 = 0.f, q0 = 0.f, q1 = 0.f;

    for (int r = wid; r < N; r += NW) {
        // self-loop (pre-scaled xw): add into the lo32 half only
        unsigned vs = xw32[((size_t)(unsigned)r << 5) | l31];
        float acc0 = lo32 ? __uint_as_float(vs << 16) : 0.0f;
        float acc1 = lo32 ? __uint_as_float(vs & 0xffff0000u) : 0.0f;

        int b = rowstart[r], e = rowstart[r + 1];
        for (int base = b; base < e; base += 64) {
            int idx = base + lane;
            int c = (idx < e) ? colA[idx] : 0;          // 64 neighbor ids, one coalesced load
            int cnt = min(64, e - base);
            int npair = cnt >> 1;
            int j = 0;
            for (; j + 3 < npair; j += 4) {
                unsigned v0 = g_rowsel(xw32, c, j,     lo32)[l31];
                unsigned v1 = g_rowsel(xw32, c, j + 1, lo32)[l31];
                unsigned v2 = g_rowsel(xw32, c, j + 2, lo32)[l31];
                unsigned v3 = g_rowsel(xw32, c, j + 3, lo32)[l31];
                acc0 += __uint_as_float(v0 << 16); acc1 += __uint_as_float(v0 & 0xffff0000u);
                acc0 += __uint_as_float(v1 << 16); acc1 += __uint_as_float(v1 & 0xffff0000u);
                acc0 += __uint_as_float(v2 << 16); acc1 += __uint_as_float(v2 & 0xffff0000u);
                acc0 += __uint_as_float(v3 << 16); acc1 += __uint_as_float(v3 & 0xffff0000u);
            }
            for (; j < npair; ++j) {
                unsigned v = g_rowsel(xw32, c, j, lo32)[l31];
                acc0 += __uint_as_float(v << 16); acc1 += __uint_as_float(v & 0xffff0000u);
            }
            if (cnt & 1) {   // odd tail edge: only lo32 half contributes
                int s = __builtin_amdgcn_readlane(c, cnt - 1);
                unsigned v = xw32[((size_t)(unsigned)s << 5) | l31];
                if (lo32) {
                    acc0 += __uint_as_float(v << 16);
                    acc1 += __uint_as_float(v & 0xffff0000u);
                }
            }
        }
        acc0 += __shfl_xor(acc0, 32);
        acc1 += __shfl_xor(acc1, 32);
        if (lo32) {
            float di = dinv[r];
            float o0 = acc0 * di, o1 = acc1 * di;
            s0 += o0; q0 += o0 * o0;
            s1 += o1; q1 += o1 * o1;
            float2 o; o.x = o0; o.y = o1;
            *(float2*)(agg + ((size_t)r << 6) + l31 * 2) = o;
        }
    }

    // block-level stats reduction (lane l31 owns cols 2*l31, 2*l31+1) — all threads reach barrier
    __shared__ float sdS[4][64];
    __shared__ float sdQ[4][64];
    if (lo32) {
        sdS[w][2 * l31] = s0; sdS[w][2 * l31 + 1] = s1;
        sdQ[w][2 * l31] = q0; sdQ[w][2 * l31 + 1] = q1;
    }
    __syncthreads();
    int t = threadIdx.x;
    if (t < 64) {
        float ss = sdS[0][t] + sdS[1][t] + sdS[2][t] + sdS[3][t];
        atomicAdd(&stats[t], ss);
    } else if (t < 128) {
        int c = t - 64;
        float qq = sdQ[0][c] + sdQ[1][c] + sdQ[2][c] + sdQ[3][c];
        atomicAdd(&stats[64 + c], qq);
    }
}

// ---------------- BN apply + ReLU + residual + rolling emb fold ----------------
// f4-vectorized. Each layer l>=1 folds w_l*v_l into emb in-register; layer 1 additionally
// folds w_0*x0 (already loaded as the residual). x-buffers ping-pong (x0 dead after layer 1).
__global__ __launch_bounds__(256) void k_elem(const float* __restrict__ agg, const float* __restrict__ stats,
                                              const float* __restrict__ gamma, const float* __restrict__ beta,
                                              const float* __restrict__ lw, const float* __restrict__ xprev,
                                              float* __restrict__ xcur, float* __restrict__ emb,
                                              int N, int layer, int L) {
    size_t i = ((size_t)blockIdx.x * 256 + threadIdx.x) * 4;
    if (i >= (size_t)N * 64) return;
    int c = (int)(i & 63);
    float rN = 1.0f / (float)N;
    f4 av = *(const f4*)(agg + i);
    f4 gv = *(const f4*)(gamma + c);
    f4 bv = *(const f4*)(beta + c);
    f4 sv = *(const f4*)(stats + c);
    f4 qv = *(const f4*)(stats + 64 + c);
    f4 v;
    #pragma unroll
    for (int j = 0; j < 4; ++j) {
        float mn = sv[j] * rN;
        float var = qv[j] * rN - mn * mn;
        float inv = rsqrtf(var + BN_EPS);
        v[j] = fmaxf((av[j] - mn) * inv * gv[j] + bv[j], 0.0f);
    }
    f4 xp = {};
    if (layer > 0) {
        xp = *(const f4*)(xprev + i);
        #pragma unroll
        for (int j = 0; j < 4; ++j) v[j] += RES_SCALE * xp[j];
    }
    if (layer < L - 1) *(f4*)(xcur + i) = v;
    if (layer == 0) return;

    // softmax over lw (L small, loads hit L2)
    float mx = lw[0];
    for (int j = 1; j < L; ++j) mx = fmaxf(mx, lw[j]);
    float sum = 0.f, wbuf[8];
    for (int j = 0; j < L; ++j) { float ee = __expf(lw[j] - mx); wbuf[j] = ee; sum += ee; }
    float rs = 1.0f / sum;
    float wl = wbuf[layer] * rs;
    f4 o;
    if (layer == 1) {
        float w0 = wbuf[0] * rs;
        #pragma unroll
        for (int j = 0; j < 4; ++j) o[j] = w0 * xp[j] + wl * v[j];
    } else {
        f4 ep = *(const f4*)(emb + i);
        #pragma unroll
        for (int j = 0; j < 4; ++j) o[j] = ep[j] + wl * v[j];
    }
    *(f4*)(emb + i) = o;
}

extern "C" void kernel_launch(void* const* d_in, const int* in_sizes, int n_in,
                              void* d_out, int out_size, void* d_ws, size_t ws_size,
                              hipStream_t stream) {
    const float* features = (const float*)d_in[0];
    const int*   edges    = (const int*)d_in[1];
    const float* W0       = (const float*)d_in[2];
    // d_in[3] = b0: cancels through BatchNorm (mean subtraction) -> skipped, exact
    const float* Wh       = (const float*)d_in[4];
    // d_in[5] = bh: same
    const float* gamma    = (const float*)d_in[6];
    const float* beta     = (const float*)d_in[7];
    const float* lw       = (const float*)d_in[8];

    const int HID    = in_sizes[3];            // 64
    const int IN_DIM = in_sizes[2] / HID;      // 2000
    const int N      = in_sizes[0] / IN_DIM;   // 50000
    const int E      = in_sizes[1] / 2;        // 1600000
    const int L      = in_sizes[8];            // 4
    float* out = (float*)d_out;

    char* ws = (char*)d_ws;
    auto alloc = [&](size_t bytes) { char* p = ws; ws += (bytes + 255) & ~(size_t)255; return p; };
    int*   counts   = (int*)alloc((size_t)N * 4);
    int*   cursor   = (int*)alloc((size_t)N * 4);
    int*   rowstart = (int*)alloc((size_t)(N + 1) * 4);
    int*   bsum     = (int*)alloc(256 * 4);
    float* dinv     = (float*)alloc((size_t)N * 4);
    float* stats    = (float*)alloc((size_t)L * 128 * 4);
    int*   colA     = (int*)alloc((size_t)E * 4);
    short* WT0      = (short*)alloc((size_t)HID * IN_DIM * 2);
    short* WTh      = (short*)alloc((size_t)(L - 1) * HID * HID * 2);
    __hip_bfloat16* xw = (__hip_bfloat16*)alloc((size_t)N * HID * 2);
    float* agg      = (float*)alloc((size_t)N * HID * 4);
    float* x0       = (float*)alloc((size_t)N * HID * 4);
    float* x1       = (float*)alloc((size_t)N * HID * 4);

    int S = L * 128;
    int zgrid = (max(N, S) + 255) / 256;
    k_zero<<<zgrid, 256, 0, stream>>>(counts, cursor, stats, N, S);

    int egrid = (E + 255) / 256;
    k_count<<<egrid, 256, 0, stream>>>(edges, E, counts);

    int B = (N + 1023) / 1024;
    k_scan1<<<B, 256, 0, stream>>>(counts, bsum, dinv, N);
    k_scan2<<<1, 64, 0, stream>>>(bsum, B, rowstart, N);
    k_scan3<<<B, 256, 0, stream>>>(counts, bsum, rowstart, N);
    k_scatter<<<egrid, 256, 0, stream>>>(edges, E, rowstart, cursor, colA);

    int nk0 = (IN_DIM + 63) / 64;
    k_wt<<<nk0 + (L - 1), 256, 0, stream>>>(W0, Wh, WT0, WTh, IN_DIM);

    int mmgrid = (N + 63) / 64;
    int ggrid  = min((N + 3) / 4, 2048);
    int NW     = ggrid * 4;   // waves in gather grid
    int elgrid = (int)(((size_t)N * HID / 4 + 255) / 256);

    float* xb[2] = { x0, x1 };
    const float* xc_prev = nullptr;
    for (int l = 0; l < L; ++l) {
        const float* Xin = (l == 0) ? features : xc_prev;
        int K = (l == 0) ? IN_DIM : HID;
        const short* WTl = (l == 0) ? WT0 : WTh + (size_t)(l - 1) * HID * HID;
        k_mm<<<mmgrid, 256, 0, stream>>>(Xin, WTl, dinv, xw, N, K);
        k_gather<<<ggrid, 256, 0, stream>>>(xw, colA, rowstart, dinv, agg, stats + l * 128, N, NW);
        float* xcur = (l < L - 1) ? xb[l & 1] : nullptr;        // ping-pong; x0 dead after layer 1
        const float* xprev = (l == 0) ? nullptr : xb[(l - 1) & 1];
        k_elem<<<elgrid, 256, 0, stream>>>(agg, stats + l * 128, gamma + l * HID, beta + l * HID,
                                           lw, xprev, xcur, out, N, l, L);
        if (l < L - 1) xc_prev = xcur;
    }
}

// Round 8
// 1000.830 us; speedup vs baseline: 1.0939x; 1.0939x over previous
//
#include <hip/hip_runtime.h>
#include <hip/hip_bf16.h>
#include <math.h>

#define BN_EPS 1e-5f
#define RES_SCALE 0.7f

typedef float f4 __attribute__((ext_vector_type(4)));
typedef short s8 __attribute__((ext_vector_type(8)));

__device__ inline short f2bf(float f) {
    __hip_bfloat16 h = __float2bfloat16(f);
    return *reinterpret_cast<short*>(&h);
}

__device__ inline float uf(unsigned u) { return __uint_as_float(u); }

// ---------------- init ----------------
__global__ __launch_bounds__(256) void k_zero(int* counts, int* cursor, float* stats, int N, int S) {
    int i = blockIdx.x * 256 + threadIdx.x;
    if (i < N) { counts[i] = 0; cursor[i] = 0; }
    if (i < S) stats[i] = 0.0f;
}

// ---------------- degree / CSR build ----------------
__global__ __launch_bounds__(256) void k_count(const int* __restrict__ edges, int E, int* __restrict__ counts) {
    int e = blockIdx.x * 256 + threadIdx.x;
    if (e < E) atomicAdd(&counts[edges[E + e]], 1);   // dst = edges[1][e]
}

// exclusive scan of counts -> rowstart (chunk = 1024 per block); also emits dinv
__global__ __launch_bounds__(256) void k_scan1(const int* __restrict__ counts, int* __restrict__ bsum,
                                               float* __restrict__ dinv, int N) {
    __shared__ int sd[256];
    int t = threadIdx.x;
    int base = blockIdx.x * 1024 + t * 4;
    int s = 0;
    if (base + 3 < N) {
        int4 v = *(const int4*)(counts + base);
        s = v.x + v.y + v.z + v.w;
        f4 d;
        d.x = rsqrtf((float)v.x + 1.0f);
        d.y = rsqrtf((float)v.y + 1.0f);
        d.z = rsqrtf((float)v.z + 1.0f);
        d.w = rsqrtf((float)v.w + 1.0f);
        *(f4*)(dinv + base) = d;
    } else {
        for (int j = 0; j < 4; ++j) if (base + j < N) {
            int cv = counts[base + j];
            s += cv;
            dinv[base + j] = rsqrtf((float)cv + 1.0f);
        }
    }
    sd[t] = s; __syncthreads();
    for (int off = 128; off > 0; off >>= 1) { if (t < off) sd[t] += sd[t + off]; __syncthreads(); }
    if (t == 0) bsum[blockIdx.x] = sd[0];
}

__global__ void k_scan2(int* bsum, int B, int* rowstart, int N) {
    if (threadIdx.x == 0 && blockIdx.x == 0) {
        int run = 0;
        for (int b = 0; b < B; ++b) { int v = bsum[b]; bsum[b] = run; run += v; }
        rowstart[N] = run;
    }
}

__global__ __launch_bounds__(256) void k_scan3(const int* __restrict__ counts, const int* __restrict__ bsum,
                                               int* __restrict__ rowstart, int N) {
    __shared__ int sd[256];
    int t = threadIdx.x;
    int base = blockIdx.x * 1024 + t * 4;
    int v0 = 0, v1 = 0, v2 = 0, v3 = 0;
    if (base + 3 < N) { int4 v = *(const int4*)(counts + base); v0 = v.x; v1 = v.y; v2 = v.z; v3 = v.w; }
    else {
        if (base < N) v0 = counts[base];
        if (base + 1 < N) v1 = counts[base + 1];
        if (base + 2 < N) v2 = counts[base + 2];
        if (base + 3 < N) v3 = counts[base + 3];
    }
    int s = v0 + v1 + v2 + v3;
    sd[t] = s; __syncthreads();
    for (int off = 1; off < 256; off <<= 1) {
        int add = (t >= off) ? sd[t - off] : 0;
        __syncthreads();
        sd[t] += add;
        __syncthreads();
    }
    int excl = sd[t] - s + bsum[blockIdx.x];
    if (base < N)     rowstart[base]     = excl;
    if (base + 1 < N) rowstart[base + 1] = excl + v0;
    if (base + 2 < N) rowstart[base + 2] = excl + v0 + v1;
    if (base + 3 < N) rowstart[base + 3] = excl + v0 + v1 + v2;
}

// scatter: CSR column list only (edge weight is folded into pre-scaled xw)
__global__ __launch_bounds__(256) void k_scatter(const int* __restrict__ edges, int E,
                                                 const int* __restrict__ rowstart, int* __restrict__ cursor,
                                                 int* __restrict__ colA) {
    int e = blockIdx.x * 256 + threadIdx.x;
    if (e >= E) return;
    int s = edges[e], d = edges[E + e];
    int pos = rowstart[d] + atomicAdd(&cursor[d], 1);
    colA[pos] = s;
}

// ---------------- W pre-transpose + bf16 convert: WT[n][k] = bf16(W[k][n]) ----------------
__global__ __launch_bounds__(256) void k_wt(const float* __restrict__ W0, const float* __restrict__ Wh,
                                            short* __restrict__ WT0, short* __restrict__ WTh, int K0) {
    __shared__ short Ts[64][72];
    int b = blockIdx.x, t = threadIdx.x;
    int nk0 = (K0 + 63) >> 6;
    const float* W; short* dst; int K, kt;
    if (b < nk0) { W = W0; dst = WT0; K = K0; kt = b * 64; }
    else { int l = b - nk0; W = Wh + (size_t)l * 64 * 64; dst = WTh + (size_t)l * 64 * 64; K = 64; kt = 0; }
    #pragma unroll
    for (int i = 0; i < 16; ++i) {
        int idx = t + i * 256;
        int r = idx >> 6, c = idx & 63;
        int gk = kt + r;
        Ts[c][r] = (gk < K) ? f2bf(W[(size_t)gk * 64 + c]) : (short)0;
    }
    __syncthreads();
    #pragma unroll
    for (int i = 0; i < 16; ++i) {
        int idx = t + i * 256;
        int n = idx >> 6, r = idx & 63;
        int gk = kt + r;
        if (gk < K) dst[(size_t)n * K + gk] = Ts[n][r];
    }
}

// ---------------- MFMA matmul: Cb[N,64] (bf16) = (X[N,K] @ WT^T) * dinv[row] ----------------
// K-tile 64; next-tile loads issued AFTER the first barrier so they stay in flight across
// the MFMA phase (compiler drains vmcnt at each barrier — issuing before a barrier kills
// the overlap; measured regression in R4).
__global__ __launch_bounds__(256) void k_mm(const float* __restrict__ X, const short* __restrict__ WT,
                                            const float* __restrict__ dinv,
                                            __hip_bfloat16* __restrict__ Cb, int N, int K) {
    __shared__ float Xs[64][68];   // row stride 272B (16B-aligned)
    __shared__ short Ws[64][72];   // row stride 144B (16B-aligned)
    int t = threadIdx.x;
    int w = t >> 6, lane = t & 63;
    int m = lane & 15, kq = lane >> 4;
    int row0 = blockIdx.x * 64;

    int xr = t >> 3, xc = t & 7;   // X staging: rows xr, xr+32; k-chunks xc*4, 32+xc*4 (float4)
    int wn = t >> 2, wc = t & 3;   // W staging: row wn, k-chunks wc*8, 32+wc*8 (8 bf16 = int4)

    f4 acc[4] = {};
    f4 px0, px1, px2, px3; int4 pw0, pw1;

    // prefetch k-tile 0
    {
        int gr0 = row0 + xr, gr1 = row0 + xr + 32;
        int gk0 = xc * 4, gk1 = 32 + xc * 4;
        px0 = (gr0 < N && gk0 < K) ? *(const f4*)(X + (size_t)gr0 * K + gk0) : (f4){};
        px1 = (gr0 < N && gk1 < K) ? *(const f4*)(X + (size_t)gr0 * K + gk1) : (f4){};
        px2 = (gr1 < N && gk0 < K) ? *(const f4*)(X + (size_t)gr1 * K + gk0) : (f4){};
        px3 = (gr1 < N && gk1 < K) ? *(const f4*)(X + (size_t)gr1 * K + gk1) : (f4){};
        int gw0 = wc * 8, gw1 = 32 + wc * 8;
        pw0 = (gw0 < K) ? *(const int4*)(WT + (size_t)wn * K + gw0) : make_int4(0, 0, 0, 0);
        pw1 = (gw1 < K) ? *(const int4*)(WT + (size_t)wn * K + gw1) : make_int4(0, 0, 0, 0);
    }

    for (int kt = 0; kt < K; kt += 64) {
        *(f4*)&Xs[xr][xc * 4]           = px0;
        *(f4*)&Xs[xr][32 + xc * 4]      = px1;
        *(f4*)&Xs[xr + 32][xc * 4]      = px2;
        *(f4*)&Xs[xr + 32][32 + xc * 4] = px3;
        *(int4*)&Ws[wn][wc * 8]         = pw0;
        *(int4*)&Ws[wn][32 + wc * 8]    = pw1;
        __syncthreads();

        int kn = kt + 64;
        if (kn < K) {
            int gr0 = row0 + xr, gr1 = row0 + xr + 32;
            int gk0 = kn + xc * 4, gk1 = kn + 32 + xc * 4;
            px0 = (gr0 < N && gk0 < K) ? *(const f4*)(X + (size_t)gr0 * K + gk0) : (f4){};
            px1 = (gr0 < N && gk1 < K) ? *(const f4*)(X + (size_t)gr0 * K + gk1) : (f4){};
            px2 = (gr1 < N && gk0 < K) ? *(const f4*)(X + (size_t)gr1 * K + gk0) : (f4){};
            px3 = (gr1 < N && gk1 < K) ? *(const f4*)(X + (size_t)gr1 * K + gk1) : (f4){};
            int gw0 = kn + wc * 8, gw1 = kn + 32 + wc * 8;
            pw0 = (gw0 < K) ? *(const int4*)(WT + (size_t)wn * K + gw0) : make_int4(0, 0, 0, 0);
            pw1 = (gw1 < K) ? *(const int4*)(WT + (size_t)wn * K + gw1) : make_int4(0, 0, 0, 0);
        }

        int arow = w * 16 + m;
        f4 a00 = *(const f4*)&Xs[arow][kq * 8];
        f4 a01 = *(const f4*)&Xs[arow][kq * 8 + 4];
        f4 a10 = *(const f4*)&Xs[arow][32 + kq * 8];
        f4 a11 = *(const f4*)&Xs[arow][32 + kq * 8 + 4];
        s8 av0, av1;
        #pragma unroll
        for (int j = 0; j < 4; ++j) {
            av0[j] = f2bf(a00[j]); av0[j + 4] = f2bf(a01[j]);
            av1[j] = f2bf(a10[j]); av1[j + 4] = f2bf(a11[j]);
        }
        #pragma unroll
        for (int ct = 0; ct < 4; ++ct) {
            s8 bv0 = *(const s8*)&Ws[ct * 16 + m][kq * 8];
            s8 bv1 = *(const s8*)&Ws[ct * 16 + m][32 + kq * 8];
            acc[ct] = __builtin_amdgcn_mfma_f32_16x16x32_bf16(av0, bv0, acc[ct], 0, 0, 0);
            acc[ct] = __builtin_amdgcn_mfma_f32_16x16x32_bf16(av1, bv1, acc[ct], 0, 0, 0);
        }
        __syncthreads();
    }

    // C/D layout: col = lane&15, row = (lane>>4)*4 + reg  [measured m89/m91]
    #pragma unroll
    for (int reg = 0; reg < 4; ++reg) {
        int gr = row0 + w * 16 + kq * 4 + reg;
        if (gr < N) {
            float di = dinv[gr];
            #pragma unroll
            for (int ct = 0; ct < 4; ++ct)
                Cb[(size_t)gr * 64 + ct * 16 + m] = __float2bfloat16(acc[ct][reg] * di);
        }
    }
}

// ---------------- CSR aggregation: one wave per dst row (dynamic load balance) ----------------
// 4 edges per wave-load: lane-group g = lane>>4 serves edge 4q+g; each lane loads uint2
// (8B = 4 bf16 cols) so one instruction fetches 512B covering 4 full xw rows. Row indices
// come from uniform readlanes + 3 per-lane selects. Cross-group reduce: 2 shfl_xor; lanes
// 0-15 write a coalesced float4.
__global__ __launch_bounds__(256) void k_gather(const __hip_bfloat16* __restrict__ xw, const int* __restrict__ colA,
                                                const int* __restrict__ rowstart,
                                                const float* __restrict__ dinv, float* __restrict__ agg, int N) {
    int wave = (blockIdx.x * 256 + threadIdx.x) >> 6;
    int lane = threadIdx.x & 63;
    if (wave >= N) return;
    int r = wave;
    const unsigned* xw32 = (const unsigned*)xw;
    int g = lane >> 4, l15 = lane & 15;
    int doff = 2 * l15;                       // dword offset within a row for this lane

    float acc0 = 0.f, acc1 = 0.f, acc2 = 0.f, acc3 = 0.f;

    // self-loop (pre-scaled xw): group 0 only
    if (g == 0) {
        uint2 v = *(const uint2*)(xw32 + (((size_t)(unsigned)r) << 5) + doff);
        acc0 += uf(v.x << 16); acc1 += uf(v.x & 0xffff0000u);
        acc2 += uf(v.y << 16); acc3 += uf(v.y & 0xffff0000u);
    }

    int b = rowstart[r], e = rowstart[r + 1];
    for (int base = b; base < e; base += 64) {
        int idx = base + lane;
        int c = (idx < e) ? colA[idx] : 0;    // 64 neighbor ids, one coalesced load
        int cnt = min(64, e - base);
        int nquad = cnt >> 2;

        #define GSEL(Q)  ({ int a0_ = __builtin_amdgcn_readlane(c, 4*(Q));     \
                            int a1_ = __builtin_amdgcn_readlane(c, 4*(Q) + 1); \
                            int a2_ = __builtin_amdgcn_readlane(c, 4*(Q) + 2); \
                            int a3_ = __builtin_amdgcn_readlane(c, 4*(Q) + 3); \
                            (g == 0) ? a0_ : (g == 1) ? a1_ : (g == 2) ? a2_ : a3_; })
        #define GACC(V)  { acc0 += uf((V).x << 16); acc1 += uf((V).x & 0xffff0000u); \
                           acc2 += uf((V).y << 16); acc3 += uf((V).y & 0xffff0000u); }

        int q = 0;
        for (; q + 3 < nquad; q += 4) {
            int s0 = GSEL(q), s1 = GSEL(q + 1), s2 = GSEL(q + 2), s3 = GSEL(q + 3);
            uint2 v0 = *(const uint2*)(xw32 + (((size_t)(unsigned)s0) << 5) + doff);
            uint2 v1 = *(const uint2*)(xw32 + (((size_t)(unsigned)s1) << 5) + doff);
            uint2 v2 = *(const uint2*)(xw32 + (((size_t)(unsigned)s2) << 5) + doff);
            uint2 v3 = *(const uint2*)(xw32 + (((size_t)(unsigned)s3) << 5) + doff);
            GACC(v0); GACC(v1); GACC(v2); GACC(v3);
        }
        for (; q < nquad; ++q) {
            int s0 = GSEL(q);
            uint2 v = *(const uint2*)(xw32 + (((size_t)(unsigned)s0) << 5) + doff);
            GACC(v);
        }
        // tail edges (cnt & 3): group 0 only
        for (int j = nquad * 4; j < cnt; ++j) {
            int s = __builtin_amdgcn_readlane(c, j);
            if (g == 0) {
                uint2 v = *(const uint2*)(xw32 + (((size_t)(unsigned)s) << 5) + doff);
                GACC(v);
            }
        }
        #undef GSEL
        #undef GACC
    }

    // reduce across the 4 lane-groups: lanes 0-15 end with the totals
    acc0 += __shfl_xor(acc0, 16); acc0 += __shfl_xor(acc0, 32);
    acc1 += __shfl_xor(acc1, 16); acc1 += __shfl_xor(acc1, 32);
    acc2 += __shfl_xor(acc2, 16); acc2 += __shfl_xor(acc2, 32);
    acc3 += __shfl_xor(acc3, 16); acc3 += __shfl_xor(acc3, 32);
    if (lane < 16) {
        float di = dinv[r];
        f4 o; o[0] = acc0 * di; o[1] = acc1 * di; o[2] = acc2 * di; o[3] = acc3 * di;
        *(f4*)(agg + ((size_t)r << 6) + l15 * 4) = o;
    }
}

// ---------------- BN stats (sum, sumsq per column) ----------------
__global__ __launch_bounds__(256) void k_stats(const float* __restrict__ x, float* __restrict__ stats, int N) {
    int col = threadIdx.x & 63;
    int sub = threadIdx.x >> 6;
    float s = 0.f, s2 = 0.f;
    for (int r = blockIdx.x * 4 + sub; r < N; r += gridDim.x * 4) {
        float v = x[(size_t)r * 64 + col];
        s += v; s2 += v * v;
    }
    __shared__ float sd[2][4][64];
    sd[0][sub][col] = s; sd[1][sub][col] = s2;
    __syncthreads();
    if (sub == 0) {
        s  = sd[0][0][col] + sd[0][1][col] + sd[0][2][col] + sd[0][3][col];
        s2 = sd[1][0][col] + sd[1][1][col] + sd[1][2][col] + sd[1][3][col];
        atomicAdd(&stats[col], s);
        atomicAdd(&stats[64 + col], s2);
    }
}

// ---------------- BN apply + ReLU + residual + rolling emb fold ----------------
// f4-vectorized. Each layer l>=1 folds w_l*v_l into emb in-register; layer 1 additionally
// folds w_0*x0 (already loaded as the residual). x-buffers ping-pong (x0 dead after layer 1).
__global__ __launch_bounds__(256) void k_elem(const float* __restrict__ agg, const float* __restrict__ stats,
                                              const float* __restrict__ gamma, const float* __restrict__ beta,
                                              const float* __restrict__ lw, const float* __restrict__ xprev,
                                              float* __restrict__ xcur, float* __restrict__ emb,
                                              int N, int layer, int L) {
    size_t i = ((size_t)blockIdx.x * 256 + threadIdx.x) * 4;
    if (i >= (size_t)N * 64) return;
    int c = (int)(i & 63);
    float rN = 1.0f / (float)N;
    f4 av = *(const f4*)(agg + i);
    f4 gv = *(const f4*)(gamma + c);
    f4 bv = *(const f4*)(beta + c);
    f4 sv = *(const f4*)(stats + c);
    f4 qv = *(const f4*)(stats + 64 + c);
    f4 v;
    #pragma unroll
    for (int j = 0; j < 4; ++j) {
        float mn = sv[j] * rN;
        float var = qv[j] * rN - mn * mn;
        float inv = rsqrtf(var + BN_EPS);
        v[j] = fmaxf((av[j] - mn) * inv * gv[j] + bv[j], 0.0f);
    }
    f4 xp = {};
    if (layer > 0) {
        xp = *(const f4*)(xprev + i);
        #pragma unroll
        for (int j = 0; j < 4; ++j) v[j] += RES_SCALE * xp[j];
    }
    if (layer < L - 1) *(f4*)(xcur + i) = v;
    if (layer == 0) return;

    // softmax over lw (L small, loads hit L2)
    float mx = lw[0];
    for (int j = 1; j < L; ++j) mx = fmaxf(mx, lw[j]);
    float sum = 0.f, wbuf[8];
    for (int j = 0; j < L; ++j) { float ee = __expf(lw[j] - mx); wbuf[j] = ee; sum += ee; }
    float rs = 1.0f / sum;
    float wl = wbuf[layer] * rs;
    f4 o;
    if (layer == 1) {
        float w0 = wbuf[0] * rs;
        #pragma unroll
        for (int j = 0; j < 4; ++j) o[j] = w0 * xp[j] + wl * v[j];
    } else {
        f4 ep = *(const f4*)(emb + i);
        #pragma unroll
        for (int j = 0; j < 4; ++j) o[j] = ep[j] + wl * v[j];
    }
    *(f4*)(emb + i) = o;
}

extern "C" void kernel_launch(void* const* d_in, const int* in_sizes, int n_in,
                              void* d_out, int out_size, void* d_ws, size_t ws_size,
                              hipStream_t stream) {
    const float* features = (const float*)d_in[0];
    const int*   edges    = (const int*)d_in[1];
    const float* W0       = (const float*)d_in[2];
    // d_in[3] = b0: cancels through BatchNorm (mean subtraction) -> skipped, exact
    const float* Wh       = (const float*)d_in[4];
    // d_in[5] = bh: same
    const float* gamma    = (const float*)d_in[6];
    const float* beta     = (const float*)d_in[7];
    const float* lw       = (const float*)d_in[8];

    const int HID    = in_sizes[3];            // 64
    const int IN_DIM = in_sizes[2] / HID;      // 2000
    const int N      = in_sizes[0] / IN_DIM;   // 50000
    const int E      = in_sizes[1] / 2;        // 1600000
    const int L      = in_sizes[8];            // 4
    float* out = (float*)d_out;

    char* ws = (char*)d_ws;
    auto alloc = [&](size_t bytes) { char* p = ws; ws += (bytes + 255) & ~(size_t)255; return p; };
    int*   counts   = (int*)alloc((size_t)N * 4);
    int*   cursor   = (int*)alloc((size_t)N * 4);
    int*   rowstart = (int*)alloc((size_t)(N + 1) * 4);
    int*   bsum     = (int*)alloc(256 * 4);
    float* dinv     = (float*)alloc((size_t)N * 4);
    float* stats    = (float*)alloc((size_t)L * 128 * 4);
    int*   colA     = (int*)alloc((size_t)E * 4);
    short* WT0      = (short*)alloc((size_t)HID * IN_DIM * 2);
    short* WTh      = (short*)alloc((size_t)(L - 1) * HID * HID * 2);
    __hip_bfloat16* xw = (__hip_bfloat16*)alloc((size_t)N * HID * 2);
    float* agg      = (float*)alloc((size_t)N * HID * 4);
    float* x0       = (float*)alloc((size_t)N * HID * 4);
    float* x1       = (float*)alloc((size_t)N * HID * 4);

    int S = L * 128;
    int zgrid = (max(N, S) + 255) / 256;
    k_zero<<<zgrid, 256, 0, stream>>>(counts, cursor, stats, N, S);

    int egrid = (E + 255) / 256;
    k_count<<<egrid, 256, 0, stream>>>(edges, E, counts);

    int B = (N + 1023) / 1024;
    k_scan1<<<B, 256, 0, stream>>>(counts, bsum, dinv, N);
    k_scan2<<<1, 64, 0, stream>>>(bsum, B, rowstart, N);
    k_scan3<<<B, 256, 0, stream>>>(counts, bsum, rowstart, N);
    k_scatter<<<egrid, 256, 0, stream>>>(edges, E, rowstart, cursor, colA);

    int nk0 = (IN_DIM + 63) / 64;
    k_wt<<<nk0 + (L - 1), 256, 0, stream>>>(W0, Wh, WT0, WTh, IN_DIM);

    int mmgrid = (N + 63) / 64;
    int ggrid  = (N + 3) / 4;
    int elgrid = (int)(((size_t)N * HID / 4 + 255) / 256);

    float* xb[2] = { x0, x1 };
    const float* xc_prev = nullptr;
    for (int l = 0; l < L; ++l) {
        const float* Xin = (l == 0) ? features : xc_prev;
        int K = (l == 0) ? IN_DIM : HID;
        const short* WTl = (l == 0) ? WT0 : WTh + (size_t)(l - 1) * HID * HID;
        k_mm<<<mmgrid, 256, 0, stream>>>(Xin, WTl, dinv, xw, N, K);
        k_gather<<<ggrid, 256, 0, stream>>>(xw, colA, rowstart, dinv, agg, N);
        k_stats<<<256, 256, 0, stream>>>(agg, stats + l * 128, N);
        float* xcur = (l < L - 1) ? xb[l & 1] : nullptr;        // ping-pong; x0 dead after layer 1
        const float* xprev = (l == 0) ? nullptr : xb[(l - 1) & 1];
        k_elem<<<elgrid, 256, 0, stream>>>(agg, stats + l * 128, gamma + l * HID, beta + l * HID,
                                           lw, xprev, xcur, out, N, l, L);
        if (l < L - 1) xc_prev = xcur;
    }
}